// Round 6
// baseline (157.692 us; speedup 1.0000x reference)
//
#include <hip/hip_runtime.h>
#include <hip/hip_bf16.h>

#define BATCH 16384
#define F_DIM 64
#define D_DIM 32
#define H_DIM 256
#define HO_DIM 128
#define NPAIR 2016
#define KSOI 2560   // 10 tiles * 256 padded slots

typedef __hip_bfloat16 bf16;
using bf16x8 = __attribute__((ext_vector_type(8))) __bf16;
using f32x4  = __attribute__((ext_vector_type(4))) float;

__device__ inline float selu_f(float v) {
    const float scale = 1.0507009873554805f;
    const float alpha = 1.6732632423543772f;
    return v > 0.f ? scale * v : scale * alpha * (__expf(v) - 1.f);
}

__device__ inline void gload16(const void* g, void* l) {
    __builtin_amdgcn_global_load_lds(
        (const __attribute__((address_space(1))) void*)g,
        (__attribute__((address_space(3))) void*)l,
        16, 0, 0);
}

// A-tile swizzle for the gram->head GEMM LDS tile (dwords within a 512B row).
// Involution: XORs bits3-4 with bits5-6 of dw, bits2-4 with row&7.
__device__ inline int soi_swz(int dw, int row) {
    return dw ^ (((dw >> 5) & 3) << 3) ^ ((row & 7) << 2);
}

// ---------------- prep: all weight repacks ----------------
__global__ void prep(const float* __restrict__ W1, const float* __restrict__ W2,
                     const float* __restrict__ W3, const float* __restrict__ Wc1,
                     bf16* __restrict__ W1T, bf16* __restrict__ W2T,
                     bf16* __restrict__ W3Tsw, bf16* __restrict__ Wc1p,
                     bf16* __restrict__ Wc1hT, bf16* __restrict__ Wc1fT) {
    const int TI[10] = {0,0,0,0,1,1,1,2,2,3};
    const int TJ[10] = {0,1,2,3,1,2,3,2,3,3};
    int bid = blockIdx.x, tid = threadIdx.x;
    if (bid < 2048) {
        int i = bid * 256 + tid;
        int n = i & 255, k = i >> 8;
        W1T[(size_t)n * 2048 + k] = __float2bfloat16(W1[i]);
    } else if (bid < 2304) {
        int i = (bid - 2048) * 256 + tid;
        int n = i & 255, k = i >> 8;
        W2T[n * 256 + k] = __float2bfloat16(W2[i]);
    } else if (bid < 2432) {
        int i = (bid - 2304) * 256 + tid;   // over 256*128, k-major
        int k = i >> 7, n = i & 127;
        W3Tsw[n * 256 + (((k >> 3) ^ (n & 7)) * 8) + (k & 7)] = __float2bfloat16(W3[i]);
    } else if (bid < 2688) {
        int n = bid - 2432;
        for (int kp = tid; kp < KSOI; kp += 256) {
            int t = kp >> 8, s = kp & 255;
            int gi = TI[t] * 16 + (s >> 4);
            int gj = TJ[t] * 16 + (s & 15);
            float v = 0.f;
            if (gi < gj) {
                int pidx = (gi * (127 - gi)) / 2 + (gj - gi - 1);
                v = Wc1[(size_t)(HO_DIM + pidx) * 256 + n];
            }
            Wc1p[(size_t)n * KSOI + kp] = __float2bfloat16(v);
        }
    } else if (bid < 2816) {
        int i = (bid - 2688) * 256 + tid;   // over 256*128
        int n = i >> 7, k = i & 127;
        Wc1hT[n * 128 + k] = __float2bfloat16(Wc1[(size_t)k * 256 + n]);
    } else {
        int i = (bid - 2816) * 256 + tid;   // over 256*32
        int n = i >> 5, k = i & 31;
        Wc1fT[n * 32 + k] = __float2bfloat16(Wc1[(size_t)(HO_DIM + NPAIR + k) * 256 + n]);
    }
}

// ---------------- K1: gram -> z partial (soi+first head) + MLP1 ----------------
__global__ __launch_bounds__(512)
__attribute__((amdgpu_waves_per_eu(2, 2))) void gram_z_mlp1(
    const float* __restrict__ x, const bf16* __restrict__ Wc1p,
    const bf16* __restrict__ Wc1fT, const bf16* __restrict__ W1T,
    const float* __restrict__ b1, float* __restrict__ z, bf16* __restrict__ h1) {
    constexpr int TI[10] = {0,0,0,0,1,1,1,2,2,3};
    constexpr int TJ[10] = {0,1,2,3,1,2,3,2,3,3};
    __shared__ __align__(16) char smraw[135168];
    bf16* Afirst = (bf16*)(smraw + 131072);
    bf16* Bsoi0  = (bf16*)(smraw + 65536);
    bf16* Bsoi1  = (bf16*)(smraw + 98304);

    const int tid = threadIdx.x;
    const int w = tid >> 6, l = tid & 63;
    const int lr = l & 15, lk = l >> 4;
    const int wm = w >> 2, wn = w & 3;
    const int blk = blockIdx.x;
    const int batch0 = blk * 64 + w * 8;
    const int srow = tid >> 3, sks = tid & 7;

    // ---- load x -> xa regs (no prefetch dbuf: saves 32 VGPR), first_order -> Afirst ----
    bf16x8 xa[8][4];
#pragma unroll
    for (int bb = 0; bb < 8; ++bb) {
        float4 f[8];
#pragma unroll
        for (int ti = 0; ti < 4; ++ti) {
            const float* p = x + (size_t)(batch0 + bb) * 2048 + (ti * 16 + lr) * 32 + lk * 8;
            f[ti * 2]     = *(const float4*)p;
            f[ti * 2 + 1] = *(const float4*)(p + 4);
        }
        float fsum[8];
#pragma unroll
        for (int j = 0; j < 8; ++j) fsum[j] = 0.f;
#pragma unroll
        for (int ti = 0; ti < 4; ++ti) {
            float4 f0 = f[ti * 2];
            float4 f1 = f[ti * 2 + 1];
            bf16x8 t;
            t[0] = (__bf16)f0.x; t[1] = (__bf16)f0.y; t[2] = (__bf16)f0.z; t[3] = (__bf16)f0.w;
            t[4] = (__bf16)f1.x; t[5] = (__bf16)f1.y; t[6] = (__bf16)f1.z; t[7] = (__bf16)f1.w;
            xa[bb][ti] = t;
            fsum[0] += f0.x; fsum[1] += f0.y; fsum[2] += f0.z; fsum[3] += f0.w;
            fsum[4] += f1.x; fsum[5] += f1.y; fsum[6] += f1.z; fsum[7] += f1.w;
        }
#pragma unroll
        for (int m = 1; m < 16; m <<= 1)
#pragma unroll
            for (int j = 0; j < 8; ++j)
                fsum[j] += __shfl_xor(fsum[j], m, 64);
        if (lr == 0) {
            bf16x8 fv;
#pragma unroll
            for (int j = 0; j < 8; ++j) fv[j] = (__bf16)fsum[j];
            *(bf16x8*)(Afirst + (w * 8 + bb) * 32 + lk * 8) = fv;
        }
    }

    // ---- gram tile 0 -> Atile[0], stage B chunk 0 ----
    const bf16* gBs[4];
#pragma unroll
    for (int s = 0; s < 4; ++s) {
        int col = s * 64 + srow;
        gBs[s] = Wc1p + (size_t)col * KSOI + ((sks ^ (col & 7)) * 8);
    }
    {
        f32x4 zero = {0.f, 0.f, 0.f, 0.f};
#pragma unroll
        for (int bb = 0; bb < 8; ++bb) {
            f32x4 g = __builtin_amdgcn_mfma_f32_16x16x32_bf16(xa[bb][0], xa[bb][0], zero, 0, 0, 0);
            int rowb = w * 8 + bb;
#pragma unroll
            for (int r = 0; r < 4; ++r) {
                int i = lk * 4 + r;
                int dw = i * 8 + (lr >> 1);
                *(bf16*)(smraw + rowb * 512 + soi_swz(dw, rowb) * 4 + (lr & 1) * 2) =
                    __float2bfloat16(g[r]);
            }
        }
#pragma unroll
        for (int s = 0; s < 4; ++s)
            gload16(gBs[s], Bsoi0 + (s * 512 + tid) * 8);
    }
    __syncthreads();

    // ---- z accumulators: first_order mini-GEMM (K=32) ----
    f32x4 acc[2][4];
    {
        bf16x8 af[2], bf_[4];
#pragma unroll
        for (int fm = 0; fm < 2; ++fm) {
            int row = wm * 32 + fm * 16 + lr;
            af[fm] = *(const bf16x8*)(Afirst + row * 32 + lk * 8);
        }
#pragma unroll
        for (int fn = 0; fn < 4; ++fn) {
            int col = wn * 64 + fn * 16 + lr;
            bf_[fn] = *(const bf16x8*)(Wc1fT + col * 32 + lk * 8);
        }
        f32x4 zero = {0.f, 0.f, 0.f, 0.f};
#pragma unroll
        for (int fm = 0; fm < 2; ++fm)
#pragma unroll
            for (int fn = 0; fn < 4; ++fn)
                acc[fm][fn] = __builtin_amdgcn_mfma_f32_16x16x32_bf16(af[fm], bf_[fn], zero, 0, 0, 0);
    }

    // ---- soi head GEMM: 40 chunks of K=64 over 10 gram tiles ----
#pragma unroll
    for (int c = 0; c < 40; ++c) {
        const int t = c >> 2;
        char* at = smraw + ((t & 1) ? 32768 : 0);
        bf16* Bc = (c & 1) ? Bsoi1 : Bsoi0;
        bf16* Bn = (c & 1) ? Bsoi0 : Bsoi1;
        if (c < 39) {
#pragma unroll
            for (int s = 0; s < 4; ++s)
                gload16(gBs[s] + (c + 1) * 64, Bn + (s * 512 + tid) * 8);
        }
        bf16x8 a[2][2], bfr[4][2];
#pragma unroll
        for (int kk2 = 0; kk2 < 2; ++kk2) {
            const int ks = (c & 3) * 2 + kk2;
#pragma unroll
            for (int fm = 0; fm < 2; ++fm) {
                int row = wm * 32 + fm * 16 + lr;
                int i = ks * 2 + (lk >> 1);
                int dw = i * 8 + (lk & 1) * 4;
                a[fm][kk2] = *(const bf16x8*)(at + row * 512 + soi_swz(dw, row) * 4);
            }
#pragma unroll
            for (int fn = 0; fn < 4; ++fn) {
                int bcol = wn * 64 + fn * 16 + lr;
                bfr[fn][kk2] = *(const bf16x8*)(Bc + bcol * 64 + (((kk2 * 4 + lk) ^ (bcol & 7)) * 8));
            }
        }
#pragma unroll
        for (int kk2 = 0; kk2 < 2; ++kk2)
#pragma unroll
            for (int fm = 0; fm < 2; ++fm)
#pragma unroll
                for (int fn = 0; fn < 4; ++fn)
                    acc[fm][fn] = __builtin_amdgcn_mfma_f32_16x16x32_bf16(
                        a[fm][kk2], bfr[fn][kk2], acc[fm][fn], 0, 0, 0);
        if ((c & 3) == 3 && t < 9) {
            char* an = smraw + (((t + 1) & 1) ? 32768 : 0);
            f32x4 zero = {0.f, 0.f, 0.f, 0.f};
#pragma unroll
            for (int bb = 0; bb < 8; ++bb) {
                f32x4 g = __builtin_amdgcn_mfma_f32_16x16x32_bf16(
                    xa[bb][TI[t + 1]], xa[bb][TJ[t + 1]], zero, 0, 0, 0);
                int rowb = w * 8 + bb;
#pragma unroll
                for (int r = 0; r < 4; ++r) {
                    int i = lk * 4 + r;
                    int dw = i * 8 + (lr >> 1);
                    *(bf16*)(an + rowb * 512 + soi_swz(dw, rowb) * 4 + (lr & 1) * 2) =
                        __float2bfloat16(g[r]);
                }
            }
        }
        __syncthreads();
    }

    // ---- store z partial (f32, row-major) ----
#pragma unroll
    for (int fm = 0; fm < 2; ++fm)
#pragma unroll
        for (int fn = 0; fn < 4; ++fn) {
            int col = wn * 64 + fn * 16 + lr;
#pragma unroll
            for (int r = 0; r < 4; ++r) {
                int row = blk * 64 + wm * 32 + fm * 16 + lk * 4 + r;
                z[(size_t)row * 256 + col] = acc[fm][fn][r];
            }
        }

    // ---------------- MLP1 phase (A from xa regs, B = W1T) ----------------
    bf16* Abuf0 = (bf16*)smraw;
    bf16* Abuf1 = (bf16*)(smraw + 8192);
    bf16* Bbuf0 = (bf16*)(smraw + 16384);
    bf16* Bbuf1 = (bf16*)(smraw + 49152);
    const bf16* gW1[4];
#pragma unroll
    for (int s = 0; s < 4; ++s) {
        int col = s * 64 + srow;
        gW1[s] = W1T + (size_t)col * 2048 + ((sks ^ (col & 7)) * 8);
    }
    int aoff[2][2], boff[4][2];
#pragma unroll
    for (int fm = 0; fm < 2; ++fm) {
        int arow = wm * 32 + fm * 16 + lr;
#pragma unroll
        for (int kk = 0; kk < 2; ++kk)
            aoff[fm][kk] = arow * 64 + (((kk * 4 + lk) ^ (arow & 7)) * 8);
    }
#pragma unroll
    for (int fn = 0; fn < 4; ++fn) {
        int bcol = wn * 64 + fn * 16 + lr;
#pragma unroll
        for (int kk = 0; kk < 2; ++kk)
            boff[fn][kk] = bcol * 64 + (((kk * 4 + lk) ^ (bcol & 7)) * 8);
    }

    f32x4 acm[2][4];
#pragma unroll
    for (int fm = 0; fm < 2; ++fm)
#pragma unroll
        for (int fn = 0; fn < 4; ++fn)
            acm[fm][fn] = (f32x4){0.f, 0.f, 0.f, 0.f};

#define WRITEA(tt, DST) { \
    const int f0_ = 2 * (tt); \
    const int lrA_ = f0_ & 15, lrB_ = (f0_ + 1) & 15; \
    int delta_ = (lr == lrA_) ? 0 : ((lr == lrB_) ? 1 : -1); \
    if (delta_ >= 0) { \
        int cs_ = delta_ * 4 + lk; \
        _Pragma("unroll") \
        for (int bb_ = 0; bb_ < 8; ++bb_) { \
            int row_ = w * 8 + bb_; \
            *(bf16x8*)((DST) + row_ * 64 + ((cs_ ^ (row_ & 7)) * 8)) = xa[bb_][(tt) >> 3]; \
        } } }

    WRITEA(0, Abuf0);
#pragma unroll
    for (int s = 0; s < 4; ++s)
        gload16(gW1[s], Bbuf0 + (s * 512 + tid) * 8);
    __syncthreads();

#pragma unroll
    for (int t = 0; t < 32; ++t) {
        bf16* Ac = (t & 1) ? Abuf1 : Abuf0;
        bf16* Bc = (t & 1) ? Bbuf1 : Bbuf0;
        bf16* An = (t & 1) ? Abuf0 : Abuf1;
        bf16* Bn = (t & 1) ? Bbuf0 : Bbuf1;
        if (t < 31) {
#pragma unroll
            for (int s = 0; s < 4; ++s)
                gload16(gW1[s] + (size_t)(t + 1) * 64, Bn + (s * 512 + tid) * 8);
        }
        bf16x8 a[2][2], bfr[4][2];
#pragma unroll
        for (int fm = 0; fm < 2; ++fm)
#pragma unroll
            for (int kk = 0; kk < 2; ++kk)
                a[fm][kk] = *(const bf16x8*)(Ac + aoff[fm][kk]);
#pragma unroll
        for (int fn = 0; fn < 4; ++fn)
#pragma unroll
            for (int kk = 0; kk < 2; ++kk)
                bfr[fn][kk] = *(const bf16x8*)(Bc + boff[fn][kk]);
#pragma unroll
        for (int kk = 0; kk < 2; ++kk)
#pragma unroll
            for (int fm = 0; fm < 2; ++fm)
#pragma unroll
                for (int fn = 0; fn < 4; ++fn)
                    acm[fm][fn] = __builtin_amdgcn_mfma_f32_16x16x32_bf16(
                        a[fm][kk], bfr[fn][kk], acm[fm][fn], 0, 0, 0);
        if (t < 31) WRITEA(t + 1, An);
        __syncthreads();
    }
#undef WRITEA

#pragma unroll
    for (int fm = 0; fm < 2; ++fm) {
#pragma unroll
        for (int fn = 0; fn < 4; ++fn) {
            int col = wn * 64 + fn * 16 + lr;
            float bv = b1[col];
#pragma unroll
            for (int r = 0; r < 4; ++r) {
                float v = selu_f(acm[fm][fn][r] + bv);
                int row = blk * 64 + wm * 32 + fm * 16 + lk * 4 + r;
                h1[(size_t)row * 256 + col] = __float2bfloat16(v);
            }
        }
    }
}

// ---------------- K2: MLP2 + MLP3 + head-hoi + relu*Wc2 -> out ----------------
__global__ __launch_bounds__(512)
__attribute__((amdgpu_waves_per_eu(2, 2))) void mlp23_head(
    const bf16* __restrict__ h1, const bf16* __restrict__ W2T, const float* __restrict__ b2,
    const bf16* __restrict__ W3Tsw, const float* __restrict__ b3,
    const bf16* __restrict__ Wc1hT, const float* __restrict__ z,
    const float* __restrict__ bc1, const float* __restrict__ Wc2,
    const float* __restrict__ bc2, float* __restrict__ Out) {
    __shared__ __align__(16) char smraw[147456];
    __shared__ float red[4][64];
    bf16* Abuf0 = (bf16*)smraw;
    bf16* Abuf1 = (bf16*)(smraw + 8192);
    bf16* Bbuf0 = (bf16*)(smraw + 16384);
    bf16* Bbuf1 = (bf16*)(smraw + 49152);
    bf16* w3l   = (bf16*)(smraw + 81920);
    bf16* h2sw  = (bf16*)smraw;
    bf16* hoisw = (bf16*)(smraw + 49152);

    const int tid = threadIdx.x;
    const int w = tid >> 6, l = tid & 63;
    const int lr = l & 15, lk = l >> 4;
    const int wm = w >> 2, wn = w & 3;
    const int rowblk = blockIdx.x * 64;
    const int srow = tid >> 3, sks = tid & 7;

#pragma unroll
    for (int s = 0; s < 8; ++s)
        gload16(W3Tsw + (size_t)(s * 512 + tid) * 8, w3l + (s * 512 + tid) * 8);

    const bf16* gA = h1 + (size_t)(rowblk + srow) * 256 + ((sks ^ (srow & 7)) * 8);
    const bf16* gBs[4];
#pragma unroll
    for (int s = 0; s < 4; ++s) {
        int col = s * 64 + srow;
        gBs[s] = W2T + (size_t)col * 256 + ((sks ^ (col & 7)) * 8);
    }
    int aoff[2][2], boff[4][2];
#pragma unroll
    for (int fm = 0; fm < 2; ++fm) {
        int arow = wm * 32 + fm * 16 + lr;
#pragma unroll
        for (int kk = 0; kk < 2; ++kk)
            aoff[fm][kk] = arow * 64 + (((kk * 4 + lk) ^ (arow & 7)) * 8);
    }
#pragma unroll
    for (int fn = 0; fn < 4; ++fn) {
        int bcol = wn * 64 + fn * 16 + lr;
#pragma unroll
        for (int kk = 0; kk < 2; ++kk)
            boff[fn][kk] = bcol * 64 + (((kk * 4 + lk) ^ (bcol & 7)) * 8);
    }

    f32x4 acc[2][4];
#pragma unroll
    for (int fm = 0; fm < 2; ++fm)
#pragma unroll
        for (int fn = 0; fn < 4; ++fn)
            acc[fm][fn] = (f32x4){0.f, 0.f, 0.f, 0.f};

    gload16(gA, Abuf0 + tid * 8);
#pragma unroll
    for (int s = 0; s < 4; ++s)
        gload16(gBs[s], Bbuf0 + (s * 512 + tid) * 8);
    __syncthreads();

#pragma unroll
    for (int t = 0; t < 4; ++t) {
        bf16* Ac = (t & 1) ? Abuf1 : Abuf0;
        bf16* Bc = (t & 1) ? Bbuf1 : Bbuf0;
        bf16* An = (t & 1) ? Abuf0 : Abuf1;
        bf16* Bn = (t & 1) ? Bbuf0 : Bbuf1;
        if (t < 3) {
            gload16(gA + (size_t)(t + 1) * 64, An + tid * 8);
#pragma unroll
            for (int s = 0; s < 4; ++s)
                gload16(gBs[s] + (size_t)(t + 1) * 64, Bn + (s * 512 + tid) * 8);
        }
        bf16x8 a[2][2], bfr[4][2];
#pragma unroll
        for (int fm = 0; fm < 2; ++fm)
#pragma unroll
            for (int kk = 0; kk < 2; ++kk)
                a[fm][kk] = *(const bf16x8*)(Ac + aoff[fm][kk]);
#pragma unroll
        for (int fn = 0; fn < 4; ++fn)
#pragma unroll
            for (int kk = 0; kk < 2; ++kk)
                bfr[fn][kk] = *(const bf16x8*)(Bc + boff[fn][kk]);
#pragma unroll
        for (int kk = 0; kk < 2; ++kk)
#pragma unroll
            for (int fm = 0; fm < 2; ++fm)
#pragma unroll
                for (int fn = 0; fn < 4; ++fn)
                    acc[fm][fn] = __builtin_amdgcn_mfma_f32_16x16x32_bf16(
                        a[fm][kk], bfr[fn][kk], acc[fm][fn], 0, 0, 0);
        __syncthreads();
    }

    // h2 (selu) -> LDS swizzled [64][256]
#pragma unroll
    for (int fm = 0; fm < 2; ++fm) {
#pragma unroll
        for (int fn = 0; fn < 4; ++fn) {
            int col = wn * 64 + fn * 16 + lr;
            float bv = b2[col];
#pragma unroll
            for (int r = 0; r < 4; ++r) {
                float v = selu_f(acc[fm][fn][r] + bv);
                int row = wm * 32 + fm * 16 + lk * 4 + r;
                h2sw[row * 256 + (((col >> 3) ^ (row & 7)) * 8) + (col & 7)] = __float2bfloat16(v);
            }
        }
    }
    __syncthreads();

    // MLP3: hoi = h2 @ W3 + b3 -> hoisw [64][128] swizzled
    f32x4 acc2[2][2];
#pragma unroll
    for (int fm = 0; fm < 2; ++fm)
#pragma unroll
        for (int fn = 0; fn < 2; ++fn)
            acc2[fm][fn] = (f32x4){0.f, 0.f, 0.f, 0.f};
#pragma unroll
    for (int ks = 0; ks < 8; ++ks) {
        bf16x8 a2[2], b2f[2];
#pragma unroll
        for (int fm = 0; fm < 2; ++fm) {
            int arow = wm * 32 + fm * 16 + lr;
            a2[fm] = *(const bf16x8*)(h2sw + arow * 256 + (((ks * 4 + lk) ^ (arow & 7)) * 8));
        }
#pragma unroll
        for (int fn = 0; fn < 2; ++fn) {
            int ncol = wn * 32 + fn * 16 + lr;
            b2f[fn] = *(const bf16x8*)(w3l + ncol * 256 + (((ks * 4 + lk) ^ (ncol & 7)) * 8));
        }
#pragma unroll
        for (int fm = 0; fm < 2; ++fm)
#pragma unroll
            for (int fn = 0; fn < 2; ++fn)
                acc2[fm][fn] = __builtin_amdgcn_mfma_f32_16x16x32_bf16(
                    a2[fm], b2f[fn], acc2[fm][fn], 0, 0, 0);
    }
#pragma unroll
    for (int fm = 0; fm < 2; ++fm) {
#pragma unroll
        for (int fn = 0; fn < 2; ++fn) {
            int col = wn * 32 + fn * 16 + lr;
            float bv = b3[col];
#pragma unroll
            for (int r = 0; r < 4; ++r) {
                float v = acc2[fm][fn][r] + bv;
                int row = wm * 32 + fm * 16 + lk * 4 + r;
                hoisw[row * 128 + (((col >> 3) ^ (row & 7)) * 8) + (col & 7)] = __float2bfloat16(v);
            }
        }
    }
    __syncthreads();

    // head-hoi: acc_h = z + hoi @ Wc1hT (K=128)
    f32x4 acch[2][4];
#pragma unroll
    for (int fm = 0; fm < 2; ++fm)
#pragma unroll
        for (int fn = 0; fn < 4; ++fn) {
            int col = wn * 64 + fn * 16 + lr;
#pragma unroll
            for (int r = 0; r < 4; ++r) {
                int row = rowblk + wm * 32 + fm * 16 + lk * 4 + r;
                acch[fm][fn][r] = z[(size_t)row * 256 + col];
            }
        }
#pragma unroll
    for (int ks = 0; ks < 4; ++ks) {
        bf16x8 a3[2], b3f[4];
#pragma unroll
        for (int fm = 0; fm < 2; ++fm) {
            int arow = wm * 32 + fm * 16 + lr;
            a3[fm] = *(const bf16x8*)(hoisw + arow * 128 + (((ks * 4 + lk) ^ (arow & 7)) * 8));
        }
#pragma unroll
        for (int fn = 0; fn < 4; ++fn) {
            int col = wn * 64 + fn * 16 + lr;
            b3f[fn] = *(const bf16x8*)(Wc1hT + col * 128 + ks * 32 + lk * 8);
        }
#pragma unroll
        for (int fm = 0; fm < 2; ++fm)
#pragma unroll
            for (int fn = 0; fn < 4; ++fn)
                acch[fm][fn] = __builtin_amdgcn_mfma_f32_16x16x32_bf16(
                    a3[fm], b3f[fn], acch[fm][fn], 0, 0, 0);
    }

    // relu + dot Wc2 + reduce -> out
    float part[2][4];
#pragma unroll
    for (int fm = 0; fm < 2; ++fm)
#pragma unroll
        for (int r = 0; r < 4; ++r) part[fm][r] = 0.f;
#pragma unroll
    for (int fm = 0; fm < 2; ++fm) {
#pragma unroll
        for (int fn = 0; fn < 4; ++fn) {
            int col = wn * 64 + fn * 16 + lr;
            float bv = bc1[col];
            float wv = Wc2[col];
#pragma unroll
            for (int r = 0; r < 4; ++r) {
                float v = fmaxf(acch[fm][fn][r] + bv, 0.f);
                part[fm][r] += v * wv;
            }
        }
    }
#pragma unroll
    for (int fm = 0; fm < 2; ++fm)
#pragma unroll
        for (int r = 0; r < 4; ++r)
#pragma unroll
            for (int m = 1; m < 16; m <<= 1)
                part[fm][r] += __shfl_xor(part[fm][r], m, 64);
    if (lr == 0) {
#pragma unroll
        for (int fm = 0; fm < 2; ++fm)
#pragma unroll
            for (int r = 0; r < 4; ++r)
                red[wn][wm * 32 + fm * 16 + lk * 4 + r] = part[fm][r];
    }
    __syncthreads();
    if (tid < 64)
        Out[rowblk + tid] = red[0][tid] + red[1][tid] + red[2][tid] + red[3][tid] + bc2[0];
}

extern "C" void kernel_launch(void* const* d_in, const int* in_sizes, int n_in,
                              void* d_out, int out_size, void* d_ws, size_t ws_size,
                              hipStream_t stream) {
    const float* x   = (const float*)d_in[0];
    const float* W1  = (const float*)d_in[1];
    const float* b1  = (const float*)d_in[2];
    const float* W2  = (const float*)d_in[3];
    const float* b2  = (const float*)d_in[4];
    const float* W3  = (const float*)d_in[5];
    const float* b3  = (const float*)d_in[6];
    const float* Wc1 = (const float*)d_in[7];
    const float* bc1 = (const float*)d_in[8];
    const float* Wc2 = (const float*)d_in[9];
    const float* bc2 = (const float*)d_in[10];
    float* out = (float*)d_out;

    char* ws = (char*)d_ws;
    bf16* W1T   = (bf16*)ws; ws += (size_t)256 * 2048 * 2;
    bf16* W2T   = (bf16*)ws; ws += (size_t)256 * 256 * 2;
    bf16* W3Tsw = (bf16*)ws; ws += (size_t)128 * 256 * 2;
    bf16* Wc1p  = (bf16*)ws; ws += (size_t)256 * KSOI * 2;
    bf16* Wc1hT = (bf16*)ws; ws += (size_t)256 * 128 * 2;
    bf16* Wc1fT = (bf16*)ws; ws += (size_t)256 * 32 * 2;
    bf16* h1    = (bf16*)ws; ws += (size_t)BATCH * H_DIM * 2;
    float* z    = (float*)ws; ws += (size_t)BATCH * 256 * 4;

    prep<<<2848, 256, 0, stream>>>(W1, W2, W3, Wc1, W1T, W2T, W3Tsw, Wc1p, Wc1hT, Wc1fT);
    gram_z_mlp1<<<256, 512, 0, stream>>>(x, Wc1p, Wc1fT, W1T, b1, z, h1);
    mlp23_head<<<256, 512, 0, stream>>>(h1, W2T, b2, W3Tsw, b3, Wc1hT, z, bc1, Wc2, bc2, out);
}

// Round 7
// 151.015 us; speedup vs baseline: 1.0442x; 1.0442x over previous
//
#include <hip/hip_runtime.h>
#include <hip/hip_bf16.h>

#define BATCH 16384
#define F_DIM 64
#define D_DIM 32
#define H_DIM 256
#define HO_DIM 128
#define NPAIR 2016
#define KSOI 2560   // 10 tiles * 256 padded slots

typedef __hip_bfloat16 bf16;
using bf16x8 = __attribute__((ext_vector_type(8))) __bf16;
using f32x4  = __attribute__((ext_vector_type(4))) float;

__device__ inline float selu_f(float v) {
    const float scale = 1.0507009873554805f;
    const float alpha = 1.6732632423543772f;
    return v > 0.f ? scale * v : scale * alpha * (__expf(v) - 1.f);
}

__device__ inline void gload16(const void* g, void* l) {
    __builtin_amdgcn_global_load_lds(
        (const __attribute__((address_space(1))) void*)g,
        (__attribute__((address_space(3))) void*)l,
        16, 0, 0);
}

// A-tile swizzle for the gram->head GEMM LDS tile (dwords within a 512B row).
// Involution: XORs bits3-4 with bits5-6 of dw, bits2-4 with row&7.
__device__ inline int soi_swz(int dw, int row) {
    return dw ^ (((dw >> 5) & 3) << 3) ^ ((row & 7) << 2);
}

// ---------------- prep: all weight repacks ----------------
__global__ void prep(const float* __restrict__ W1, const float* __restrict__ W2,
                     const float* __restrict__ W3, const float* __restrict__ Wc1,
                     bf16* __restrict__ W1T, bf16* __restrict__ W2T,
                     bf16* __restrict__ W3Tsw, bf16* __restrict__ Wc1p,
                     bf16* __restrict__ Wc1hT, bf16* __restrict__ Wc1fT) {
    const int TI[10] = {0,0,0,0,1,1,1,2,2,3};
    const int TJ[10] = {0,1,2,3,1,2,3,2,3,3};
    int bid = blockIdx.x, tid = threadIdx.x;
    if (bid < 2048) {
        int i = bid * 256 + tid;
        int n = i & 255, k = i >> 8;
        W1T[(size_t)n * 2048 + k] = __float2bfloat16(W1[i]);
    } else if (bid < 2304) {
        int i = (bid - 2048) * 256 + tid;
        int n = i & 255, k = i >> 8;
        W2T[n * 256 + k] = __float2bfloat16(W2[i]);
    } else if (bid < 2432) {
        int i = (bid - 2304) * 256 + tid;   // over 256*128, k-major
        int k = i >> 7, n = i & 127;
        W3Tsw[n * 256 + (((k >> 3) ^ (n & 7)) * 8) + (k & 7)] = __float2bfloat16(W3[i]);
    } else if (bid < 2688) {
        int n = bid - 2432;
        for (int kp = tid; kp < KSOI; kp += 256) {
            int t = kp >> 8, s = kp & 255;
            int gi = TI[t] * 16 + (s >> 4);
            int gj = TJ[t] * 16 + (s & 15);
            float v = 0.f;
            if (gi < gj) {
                int pidx = (gi * (127 - gi)) / 2 + (gj - gi - 1);
                v = Wc1[(size_t)(HO_DIM + pidx) * 256 + n];
            }
            Wc1p[(size_t)n * KSOI + kp] = __float2bfloat16(v);
        }
    } else if (bid < 2816) {
        int i = (bid - 2688) * 256 + tid;   // over 256*128
        int n = i >> 7, k = i & 127;
        Wc1hT[n * 128 + k] = __float2bfloat16(Wc1[(size_t)k * 256 + n]);
    } else {
        int i = (bid - 2816) * 256 + tid;   // over 256*32
        int n = i >> 5, k = i & 31;
        Wc1fT[n * 32 + k] = __float2bfloat16(Wc1[(size_t)(HO_DIM + NPAIR + k) * 256 + n]);
    }
}

// ---------------- K1: gram -> z partial (soi+first head) + MLP1 ----------------
// 512 blocks x 512 threads: 32 batches/block, 4 batches/wave (xa[4][4] = 32 VGPR).
// Wave grid 1x8: each wave covers rows 0..31, cols w*32..w*32+31.
// LDS: A dbuf [32][512B] x2 @ 0/16K; B dbuf 32KB x2 @ 32K/64K; Afirst @ 96K.
// MLP1 reuses: Abuf [32][64]bf16 x2 @ 0/8K; Bbuf 32KB x2 @ 16K/48K.
__global__ __launch_bounds__(512) void gram_z_mlp1(
    const float* __restrict__ x, const bf16* __restrict__ Wc1p,
    const bf16* __restrict__ Wc1fT, const bf16* __restrict__ W1T,
    const float* __restrict__ b1, float* __restrict__ z, bf16* __restrict__ h1) {
    constexpr int TI[10] = {0,0,0,0,1,1,1,2,2,3};
    constexpr int TJ[10] = {0,1,2,3,1,2,3,2,3,3};
    __shared__ __align__(16) char smraw[100352];
    bf16* Afirst = (bf16*)(smraw + 98304);

    const int tid = threadIdx.x;
    const int w = tid >> 6, l = tid & 63;
    const int lr = l & 15, lk = l >> 4;
    const int blk = blockIdx.x;
    const int batch0 = blk * 32 + w * 4;
    const int srow = tid >> 3, sks = tid & 7;

    // ---- load x -> xa regs, first_order -> Afirst ----
    bf16x8 xa[4][4];
#pragma unroll
    for (int bb = 0; bb < 4; ++bb) {
        float4 f[8];
#pragma unroll
        for (int ti = 0; ti < 4; ++ti) {
            const float* p = x + (size_t)(batch0 + bb) * 2048 + (ti * 16 + lr) * 32 + lk * 8;
            f[ti * 2]     = *(const float4*)p;
            f[ti * 2 + 1] = *(const float4*)(p + 4);
        }
        float fsum[8];
#pragma unroll
        for (int j = 0; j < 8; ++j) fsum[j] = 0.f;
#pragma unroll
        for (int ti = 0; ti < 4; ++ti) {
            float4 f0 = f[ti * 2];
            float4 f1 = f[ti * 2 + 1];
            bf16x8 t;
            t[0] = (__bf16)f0.x; t[1] = (__bf16)f0.y; t[2] = (__bf16)f0.z; t[3] = (__bf16)f0.w;
            t[4] = (__bf16)f1.x; t[5] = (__bf16)f1.y; t[6] = (__bf16)f1.z; t[7] = (__bf16)f1.w;
            xa[bb][ti] = t;
            fsum[0] += f0.x; fsum[1] += f0.y; fsum[2] += f0.z; fsum[3] += f0.w;
            fsum[4] += f1.x; fsum[5] += f1.y; fsum[6] += f1.z; fsum[7] += f1.w;
        }
#pragma unroll
        for (int m = 1; m < 16; m <<= 1)
#pragma unroll
            for (int j = 0; j < 8; ++j)
                fsum[j] += __shfl_xor(fsum[j], m, 64);
        if (lr == 0) {
            bf16x8 fv;
#pragma unroll
            for (int j = 0; j < 8; ++j) fv[j] = (__bf16)fsum[j];
            *(bf16x8*)(Afirst + (w * 4 + bb) * 32 + lk * 8) = fv;
        }
    }

    // ---- gram tile 0 -> A buf 0, stage B chunk 0 ----
    const bf16* gBs[4];
#pragma unroll
    for (int s = 0; s < 4; ++s) {
        int col = s * 64 + srow;
        gBs[s] = Wc1p + (size_t)col * KSOI + ((sks ^ (col & 7)) * 8);
    }
    {
        f32x4 zero = {0.f, 0.f, 0.f, 0.f};
#pragma unroll
        for (int bb = 0; bb < 4; ++bb) {
            f32x4 g = __builtin_amdgcn_mfma_f32_16x16x32_bf16(xa[bb][0], xa[bb][0], zero, 0, 0, 0);
            int rowb = w * 4 + bb;
#pragma unroll
            for (int r = 0; r < 4; ++r) {
                int i = lk * 4 + r;
                int dw = i * 8 + (lr >> 1);
                *(bf16*)(smraw + rowb * 512 + soi_swz(dw, rowb) * 4 + (lr & 1) * 2) =
                    __float2bfloat16(g[r]);
            }
        }
        bf16* B0 = (bf16*)(smraw + 32768);
#pragma unroll
        for (int s = 0; s < 4; ++s)
            gload16(gBs[s], B0 + (s * 512 + tid) * 8);
    }
    __syncthreads();

    // ---- z accumulators: first_order mini-GEMM (K=32) ----
    f32x4 acc[2][2];
    {
        bf16x8 af[2], bf_[2];
#pragma unroll
        for (int fm = 0; fm < 2; ++fm) {
            int row = fm * 16 + lr;
            af[fm] = *(const bf16x8*)(Afirst + row * 32 + lk * 8);
        }
#pragma unroll
        for (int fn = 0; fn < 2; ++fn) {
            int col = w * 32 + fn * 16 + lr;
            bf_[fn] = *(const bf16x8*)(Wc1fT + col * 32 + lk * 8);
        }
        f32x4 zero = {0.f, 0.f, 0.f, 0.f};
#pragma unroll
        for (int fm = 0; fm < 2; ++fm)
#pragma unroll
            for (int fn = 0; fn < 2; ++fn)
                acc[fm][fn] = __builtin_amdgcn_mfma_f32_16x16x32_bf16(af[fm], bf_[fn], zero, 0, 0, 0);
    }

    // ---- soi head GEMM: 10 tiles x 4 chunks of K=64 ----
#pragma unroll
    for (int t = 0; t < 10; ++t) {
#pragma unroll
        for (int cc = 0; cc < 4; ++cc) {
            const int c = t * 4 + cc;
            char* at = smraw + ((t & 1) ? 16384 : 0);
            bf16* Bc = (bf16*)(smraw + 32768 + ((c & 1) ? 32768 : 0));
            bf16* Bn = (bf16*)(smraw + 32768 + ((c & 1) ? 0 : 32768));
            if (c < 39) {
#pragma unroll
                for (int s = 0; s < 4; ++s)
                    gload16(gBs[s] + (c + 1) * 64, Bn + (s * 512 + tid) * 8);
            }
            bf16x8 a[2][2], bfr[2][2];
#pragma unroll
            for (int kk2 = 0; kk2 < 2; ++kk2) {
                const int ks = cc * 2 + kk2;
#pragma unroll
                for (int fm = 0; fm < 2; ++fm) {
                    int row = fm * 16 + lr;
                    int i = ks * 2 + (lk >> 1);
                    int dw = i * 8 + (lk & 1) * 4;
                    a[fm][kk2] = *(const bf16x8*)(at + row * 512 + soi_swz(dw, row) * 4);
                }
#pragma unroll
                for (int fn = 0; fn < 2; ++fn) {
                    int bcol = w * 32 + fn * 16 + lr;
                    bfr[fn][kk2] = *(const bf16x8*)(Bc + bcol * 64 + (((kk2 * 4 + lk) ^ (bcol & 7)) * 8));
                }
            }
#pragma unroll
            for (int kk2 = 0; kk2 < 2; ++kk2)
#pragma unroll
                for (int fm = 0; fm < 2; ++fm)
#pragma unroll
                    for (int fn = 0; fn < 2; ++fn)
                        acc[fm][fn] = __builtin_amdgcn_mfma_f32_16x16x32_bf16(
                            a[fm][kk2], bfr[fn][kk2], acc[fm][fn], 0, 0, 0);
            if (cc == 3 && t < 9) {
                char* an = smraw + (((t + 1) & 1) ? 16384 : 0);
                f32x4 zero = {0.f, 0.f, 0.f, 0.f};
#pragma unroll
                for (int bb = 0; bb < 4; ++bb) {
                    f32x4 g = __builtin_amdgcn_mfma_f32_16x16x32_bf16(
                        xa[bb][TI[t + 1]], xa[bb][TJ[t + 1]], zero, 0, 0, 0);
                    int rowb = w * 4 + bb;
#pragma unroll
                    for (int r = 0; r < 4; ++r) {
                        int i = lk * 4 + r;
                        int dw = i * 8 + (lr >> 1);
                        *(bf16*)(an + rowb * 512 + soi_swz(dw, rowb) * 4 + (lr & 1) * 2) =
                            __float2bfloat16(g[r]);
                    }
                }
            }
            __syncthreads();
        }
    }

    // ---- store z partial (f32, row-major) ----
#pragma unroll
    for (int fm = 0; fm < 2; ++fm)
#pragma unroll
        for (int fn = 0; fn < 2; ++fn) {
            int col = w * 32 + fn * 16 + lr;
#pragma unroll
            for (int r = 0; r < 4; ++r) {
                int row = blk * 32 + fm * 16 + lk * 4 + r;
                z[(size_t)row * 256 + col] = acc[fm][fn][r];
            }
        }

    // ---------------- MLP1 phase (A from xa regs, B = W1T) ----------------
    bf16* Abuf0 = (bf16*)smraw;
    bf16* Abuf1 = (bf16*)(smraw + 8192);
    bf16* Bbuf0 = (bf16*)(smraw + 16384);
    bf16* Bbuf1 = (bf16*)(smraw + 49152);
    const bf16* gW1[4];
#pragma unroll
    for (int s = 0; s < 4; ++s) {
        int col = s * 64 + srow;
        gW1[s] = W1T + (size_t)col * 2048 + ((sks ^ (col & 7)) * 8);
    }
    int aoff[2][2], boff[2][2];
#pragma unroll
    for (int fm = 0; fm < 2; ++fm) {
        int arow = fm * 16 + lr;
#pragma unroll
        for (int kk = 0; kk < 2; ++kk)
            aoff[fm][kk] = arow * 64 + (((kk * 4 + lk) ^ (arow & 7)) * 8);
    }
#pragma unroll
    for (int fn = 0; fn < 2; ++fn) {
        int bcol = w * 32 + fn * 16 + lr;
#pragma unroll
        for (int kk = 0; kk < 2; ++kk)
            boff[fn][kk] = bcol * 64 + (((kk * 4 + lk) ^ (bcol & 7)) * 8);
    }

    f32x4 acm[2][2];
#pragma unroll
    for (int fm = 0; fm < 2; ++fm)
#pragma unroll
        for (int fn = 0; fn < 2; ++fn)
            acm[fm][fn] = (f32x4){0.f, 0.f, 0.f, 0.f};

#define WRITEA(tt, DST) { \
    const int f0_ = 2 * (tt); \
    const int lrA_ = f0_ & 15, lrB_ = (f0_ + 1) & 15; \
    int delta_ = (lr == lrA_) ? 0 : ((lr == lrB_) ? 1 : -1); \
    if (delta_ >= 0) { \
        int cs_ = delta_ * 4 + lk; \
        _Pragma("unroll") \
        for (int bb_ = 0; bb_ < 4; ++bb_) { \
            int row_ = w * 4 + bb_; \
            *(bf16x8*)((DST) + row_ * 64 + ((cs_ ^ (row_ & 7)) * 8)) = xa[bb_][(tt) >> 3]; \
        } } }

    WRITEA(0, Abuf0);
#pragma unroll
    for (int s = 0; s < 4; ++s)
        gload16(gW1[s], Bbuf0 + (s * 512 + tid) * 8);
    __syncthreads();

#pragma unroll
    for (int t = 0; t < 32; ++t) {
        bf16* Ac = (t & 1) ? Abuf1 : Abuf0;
        bf16* Bc = (t & 1) ? Bbuf1 : Bbuf0;
        bf16* An = (t & 1) ? Abuf0 : Abuf1;
        bf16* Bn = (t & 1) ? Bbuf0 : Bbuf1;
        if (t < 31) {
#pragma unroll
            for (int s = 0; s < 4; ++s)
                gload16(gW1[s] + (size_t)(t + 1) * 64, Bn + (s * 512 + tid) * 8);
        }
        bf16x8 a[2][2], bfr[2][2];
#pragma unroll
        for (int fm = 0; fm < 2; ++fm)
#pragma unroll
            for (int kk = 0; kk < 2; ++kk)
                a[fm][kk] = *(const bf16x8*)(Ac + aoff[fm][kk]);
#pragma unroll
        for (int fn = 0; fn < 2; ++fn)
#pragma unroll
            for (int kk = 0; kk < 2; ++kk)
                bfr[fn][kk] = *(const bf16x8*)(Bc + boff[fn][kk]);
#pragma unroll
        for (int kk = 0; kk < 2; ++kk)
#pragma unroll
            for (int fm = 0; fm < 2; ++fm)
#pragma unroll
                for (int fn = 0; fn < 2; ++fn)
                    acm[fm][fn] = __builtin_amdgcn_mfma_f32_16x16x32_bf16(
                        a[fm][kk], bfr[fn][kk], acm[fm][fn], 0, 0, 0);
        if (t < 31) WRITEA(t + 1, An);
        __syncthreads();
    }
#undef WRITEA

#pragma unroll
    for (int fm = 0; fm < 2; ++fm) {
#pragma unroll
        for (int fn = 0; fn < 2; ++fn) {
            int col = w * 32 + fn * 16 + lr;
            float bv = b1[col];
#pragma unroll
            for (int r = 0; r < 4; ++r) {
                float v = selu_f(acm[fm][fn][r] + bv);
                int row = blk * 32 + fm * 16 + lk * 4 + r;
                h1[(size_t)row * 256 + col] = __float2bfloat16(v);
            }
        }
    }
}

// ---------------- K2: MLP2 + MLP3 + head-hoi + relu*Wc2 -> out ----------------
__global__ __launch_bounds__(512) void mlp23_head(
    const bf16* __restrict__ h1, const bf16* __restrict__ W2T, const float* __restrict__ b2,
    const bf16* __restrict__ W3Tsw, const float* __restrict__ b3,
    const bf16* __restrict__ Wc1hT, const float* __restrict__ z,
    const float* __restrict__ bc1, const float* __restrict__ Wc2,
    const float* __restrict__ bc2, float* __restrict__ Out) {
    __shared__ __align__(16) char smraw[147456];
    __shared__ float red[4][64];
    bf16* Abuf0 = (bf16*)smraw;
    bf16* Abuf1 = (bf16*)(smraw + 8192);
    bf16* Bbuf0 = (bf16*)(smraw + 16384);
    bf16* Bbuf1 = (bf16*)(smraw + 49152);
    bf16* w3l   = (bf16*)(smraw + 81920);
    bf16* h2sw  = (bf16*)smraw;
    bf16* hoisw = (bf16*)(smraw + 49152);

    const int tid = threadIdx.x;
    const int w = tid >> 6, l = tid & 63;
    const int lr = l & 15, lk = l >> 4;
    const int wm = w >> 2, wn = w & 3;
    const int rowblk = blockIdx.x * 64;
    const int srow = tid >> 3, sks = tid & 7;

#pragma unroll
    for (int s = 0; s < 8; ++s)
        gload16(W3Tsw + (size_t)(s * 512 + tid) * 8, w3l + (s * 512 + tid) * 8);

    const bf16* gA = h1 + (size_t)(rowblk + srow) * 256 + ((sks ^ (srow & 7)) * 8);
    const bf16* gBs[4];
#pragma unroll
    for (int s = 0; s < 4; ++s) {
        int col = s * 64 + srow;
        gBs[s] = W2T + (size_t)col * 256 + ((sks ^ (col & 7)) * 8);
    }
    int aoff[2][2], boff[4][2];
#pragma unroll
    for (int fm = 0; fm < 2; ++fm) {
        int arow = wm * 32 + fm * 16 + lr;
#pragma unroll
        for (int kk = 0; kk < 2; ++kk)
            aoff[fm][kk] = arow * 64 + (((kk * 4 + lk) ^ (arow & 7)) * 8);
    }
#pragma unroll
    for (int fn = 0; fn < 4; ++fn) {
        int bcol = wn * 64 + fn * 16 + lr;
#pragma unroll
        for (int kk = 0; kk < 2; ++kk)
            boff[fn][kk] = bcol * 64 + (((kk * 4 + lk) ^ (bcol & 7)) * 8);
    }

    f32x4 acc[2][4];
#pragma unroll
    for (int fm = 0; fm < 2; ++fm)
#pragma unroll
        for (int fn = 0; fn < 4; ++fn)
            acc[fm][fn] = (f32x4){0.f, 0.f, 0.f, 0.f};

    gload16(gA, Abuf0 + tid * 8);
#pragma unroll
    for (int s = 0; s < 4; ++s)
        gload16(gBs[s], Bbuf0 + (s * 512 + tid) * 8);
    __syncthreads();

#pragma unroll
    for (int t = 0; t < 4; ++t) {
        bf16* Ac = (t & 1) ? Abuf1 : Abuf0;
        bf16* Bc = (t & 1) ? Bbuf1 : Bbuf0;
        bf16* An = (t & 1) ? Abuf0 : Abuf1;
        bf16* Bn = (t & 1) ? Bbuf0 : Bbuf1;
        if (t < 3) {
            gload16(gA + (size_t)(t + 1) * 64, An + tid * 8);
#pragma unroll
            for (int s = 0; s < 4; ++s)
                gload16(gBs[s] + (size_t)(t + 1) * 64, Bn + (s * 512 + tid) * 8);
        }
        bf16x8 a[2][2], bfr[4][2];
#pragma unroll
        for (int fm = 0; fm < 2; ++fm)
#pragma unroll
            for (int kk = 0; kk < 2; ++kk)
                a[fm][kk] = *(const bf16x8*)(Ac + aoff[fm][kk]);
#pragma unroll
        for (int fn = 0; fn < 4; ++fn)
#pragma unroll
            for (int kk = 0; kk < 2; ++kk)
                bfr[fn][kk] = *(const bf16x8*)(Bc + boff[fn][kk]);
#pragma unroll
        for (int kk = 0; kk < 2; ++kk)
#pragma unroll
            for (int fm = 0; fm < 2; ++fm)
#pragma unroll
                for (int fn = 0; fn < 4; ++fn)
                    acc[fm][fn] = __builtin_amdgcn_mfma_f32_16x16x32_bf16(
                        a[fm][kk], bfr[fn][kk], acc[fm][fn], 0, 0, 0);
        __syncthreads();
    }

    // h2 (selu) -> LDS swizzled [64][256]
#pragma unroll
    for (int fm = 0; fm < 2; ++fm) {
#pragma unroll
        for (int fn = 0; fn < 4; ++fn) {
            int col = wn * 64 + fn * 16 + lr;
            float bv = b2[col];
#pragma unroll
            for (int r = 0; r < 4; ++r) {
                float v = selu_f(acc[fm][fn][r] + bv);
                int row = wm * 32 + fm * 16 + lk * 4 + r;
                h2sw[row * 256 + (((col >> 3) ^ (row & 7)) * 8) + (col & 7)] = __float2bfloat16(v);
            }
        }
    }
    __syncthreads();

    // MLP3: hoi = h2 @ W3 + b3 -> hoisw [64][128] swizzled
    f32x4 acc2[2][2];
#pragma unroll
    for (int fm = 0; fm < 2; ++fm)
#pragma unroll
        for (int fn = 0; fn < 2; ++fn)
            acc2[fm][fn] = (f32x4){0.f, 0.f, 0.f, 0.f};
#pragma unroll
    for (int ks = 0; ks < 8; ++ks) {
        bf16x8 a2[2], b2f[2];
#pragma unroll
        for (int fm = 0; fm < 2; ++fm) {
            int arow = wm * 32 + fm * 16 + lr;
            a2[fm] = *(const bf16x8*)(h2sw + arow * 256 + (((ks * 4 + lk) ^ (arow & 7)) * 8));
        }
#pragma unroll
        for (int fn = 0; fn < 2; ++fn) {
            int ncol = wn * 32 + fn * 16 + lr;
            b2f[fn] = *(const bf16x8*)(w3l + ncol * 256 + (((ks * 4 + lk) ^ (ncol & 7)) * 8));
        }
#pragma unroll
        for (int fm = 0; fm < 2; ++fm)
#pragma unroll
            for (int fn = 0; fn < 2; ++fn)
                acc2[fm][fn] = __builtin_amdgcn_mfma_f32_16x16x32_bf16(
                    a2[fm], b2f[fn], acc2[fm][fn], 0, 0, 0);
    }
#pragma unroll
    for (int fm = 0; fm < 2; ++fm) {
#pragma unroll
        for (int fn = 0; fn < 2; ++fn) {
            int col = wn * 32 + fn * 16 + lr;
            float bv = b3[col];
#pragma unroll
            for (int r = 0; r < 4; ++r) {
                float v = acc2[fm][fn][r] + bv;
                int row = wm * 32 + fm * 16 + lk * 4 + r;
                hoisw[row * 128 + (((col >> 3) ^ (row & 7)) * 8) + (col & 7)] = __float2bfloat16(v);
            }
        }
    }
    __syncthreads();

    // head-hoi: acc_h = z + hoi @ Wc1hT (K=128)
    f32x4 acch[2][4];
#pragma unroll
    for (int fm = 0; fm < 2; ++fm)
#pragma unroll
        for (int fn = 0; fn < 4; ++fn) {
            int col = wn * 64 + fn * 16 + lr;
#pragma unroll
            for (int r = 0; r < 4; ++r) {
                int row = rowblk + wm * 32 + fm * 16 + lk * 4 + r;
                acch[fm][fn][r] = z[(size_t)row * 256 + col];
            }
        }
#pragma unroll
    for (int ks = 0; ks < 4; ++ks) {
        bf16x8 a3[2], b3f[4];
#pragma unroll
        for (int fm = 0; fm < 2; ++fm) {
            int arow = wm * 32 + fm * 16 + lr;
            a3[fm] = *(const bf16x8*)(hoisw + arow * 128 + (((ks * 4 + lk) ^ (arow & 7)) * 8));
        }
#pragma unroll
        for (int fn = 0; fn < 4; ++fn) {
            int col = wn * 64 + fn * 16 + lr;
            b3f[fn] = *(const bf16x8*)(Wc1hT + col * 128 + ks * 32 + lk * 8);
        }
#pragma unroll
        for (int fm = 0; fm < 2; ++fm)
#pragma unroll
            for (int fn = 0; fn < 4; ++fn)
                acch[fm][fn] = __builtin_amdgcn_mfma_f32_16x16x32_bf16(
                    a3[fm], b3f[fn], acch[fm][fn], 0, 0, 0);
    }

    // relu + dot Wc2 + reduce -> out
    float part[2][4];
#pragma unroll
    for (int fm = 0; fm < 2; ++fm)
#pragma unroll
        for (int r = 0; r < 4; ++r) part[fm][r] = 0.f;
#pragma unroll
    for (int fm = 0; fm < 2; ++fm) {
#pragma unroll
        for (int fn = 0; fn < 4; ++fn) {
            int col = wn * 64 + fn * 16 + lr;
            float bv = bc1[col];
            float wv = Wc2[col];
#pragma unroll
            for (int r = 0; r < 4; ++r) {
                float v = fmaxf(acch[fm][fn][r] + bv, 0.f);
                part[fm][r] += v * wv;
            }
        }
    }
#pragma unroll
    for (int fm = 0; fm < 2; ++fm)
#pragma unroll
        for (int r = 0; r < 4; ++r)
#pragma unroll
            for (int m = 1; m < 16; m <<= 1)
                part[fm][r] += __shfl_xor(part[fm][r], m, 64);
    if (lr == 0) {
#pragma unroll
        for (int fm = 0; fm < 2; ++fm)
#pragma unroll
            for (int r = 0; r < 4; ++r)
                red[wn][wm * 32 + fm * 16 + lk * 4 + r] = part[fm][r];
    }
    __syncthreads();
    if (tid < 64)
        Out[rowblk + tid] = red[0][tid] + red[1][tid] + red[2][tid] + red[3][tid] + bc2[0];
}

extern "C" void kernel_launch(void* const* d_in, const int* in_sizes, int n_in,
                              void* d_out, int out_size, void* d_ws, size_t ws_size,
                              hipStream_t stream) {
    const float* x   = (const float*)d_in[0];
    const float* W1  = (const float*)d_in[1];
    const float* b1  = (const float*)d_in[2];
    const float* W2  = (const float*)d_in[3];
    const float* b2  = (const float*)d_in[4];
    const float* W3  = (const float*)d_in[5];
    const float* b3  = (const float*)d_in[6];
    const float* Wc1 = (const float*)d_in[7];
    const float* bc1 = (const float*)d_in[8];
    const float* Wc2 = (const float*)d_in[9];
    const float* bc2 = (const float*)d_in[10];
    float* out = (float*)d_out;

    char* ws = (char*)d_ws;
    bf16* W1T   = (bf16*)ws; ws += (size_t)256 * 2048 * 2;
    bf16* W2T   = (bf16*)ws; ws += (size_t)256 * 256 * 2;
    bf16* W3Tsw = (bf16*)ws; ws += (size_t)128 * 256 * 2;
    bf16* Wc1p  = (bf16*)ws; ws += (size_t)256 * KSOI * 2;
    bf16* Wc1hT = (bf16*)ws; ws += (size_t)256 * 128 * 2;
    bf16* Wc1fT = (bf16*)ws; ws += (size_t)256 * 32 * 2;
    bf16* h1    = (bf16*)ws; ws += (size_t)BATCH * H_DIM * 2;
    float* z    = (float*)ws; ws += (size_t)BATCH * 256 * 4;

    prep<<<2848, 256, 0, stream>>>(W1, W2, W3, Wc1, W1T, W2T, W3Tsw, Wc1p, Wc1hT, Wc1fT);
    gram_z_mlp1<<<512, 512, 0, stream>>>(x, Wc1p, Wc1fT, W1T, b1, z, h1);
    mlp23_head<<<256, 512, 0, stream>>>(h1, W2T, b2, W3Tsw, b3, Wc1hT, z, bc1, Wc2, bc2, out);
}

// Round 11
// 144.549 us; speedup vs baseline: 1.0909x; 1.0447x over previous
//
#include <hip/hip_runtime.h>
#include <hip/hip_bf16.h>

#define BATCH 16384
#define F_DIM 64
#define D_DIM 32
#define H_DIM 256
#define HO_DIM 128
#define NPAIR 2016
#define KSOI 2560   // 10 tiles * 256 padded slots

typedef __hip_bfloat16 bf16;
using bf16x8 = __attribute__((ext_vector_type(8))) __bf16;
using f32x4  = __attribute__((ext_vector_type(4))) float;

__device__ inline float selu_f(float v) {
    const float scale = 1.0507009873554805f;
    const float alpha = 1.6732632423543772f;
    return v > 0.f ? scale * v : scale * alpha * (__expf(v) - 1.f);
}

__device__ inline void gload16(const void* g, void* l) {
    __builtin_amdgcn_global_load_lds(
        (const __attribute__((address_space(1))) void*)g,
        (__attribute__((address_space(3))) void*)l,
        16, 0, 0);
}

// soi A-tile swizzle (dwords within a 512B row). R7-proven.
__device__ inline int soi_swz(int dw, int row) {
    return dw ^ (((dw >> 5) & 3) << 3) ^ ((row & 7) << 2);
}

// ---------------- prep: all weight repacks (R7 verbatim) ----------------
__global__ void prep(const float* __restrict__ W1, const float* __restrict__ W2,
                     const float* __restrict__ W3, const float* __restrict__ Wc1,
                     bf16* __restrict__ W1T, bf16* __restrict__ W2T,
                     bf16* __restrict__ W3Tsw, bf16* __restrict__ Wc1p,
                     bf16* __restrict__ Wc1hT, bf16* __restrict__ Wc1fT) {
    const int TI[10] = {0,0,0,0,1,1,1,2,2,3};
    const int TJ[10] = {0,1,2,3,1,2,3,2,3,3};
    int bid = blockIdx.x, tid = threadIdx.x;
    if (bid < 2048) {
        int i = bid * 256 + tid;
        int n = i & 255, k = i >> 8;
        W1T[(size_t)n * 2048 + k] = __float2bfloat16(W1[i]);
    } else if (bid < 2304) {
        int i = (bid - 2048) * 256 + tid;
        int n = i & 255, k = i >> 8;
        W2T[n * 256 + k] = __float2bfloat16(W2[i]);
    } else if (bid < 2432) {
        int i = (bid - 2304) * 256 + tid;   // over 256*128, k-major
        int k = i >> 7, n = i & 127;
        W3Tsw[n * 256 + (((k >> 3) ^ (n & 7)) * 8) + (k & 7)] = __float2bfloat16(W3[i]);
    } else if (bid < 2688) {
        int n = bid - 2432;
        for (int kp = tid; kp < KSOI; kp += 256) {
            int t = kp >> 8, s = kp & 255;
            int gi = TI[t] * 16 + (s >> 4);
            int gj = TJ[t] * 16 + (s & 15);
            float v = 0.f;
            if (gi < gj) {
                int pidx = (gi * (127 - gi)) / 2 + (gj - gi - 1);
                v = Wc1[(size_t)(HO_DIM + pidx) * 256 + n];
            }
            Wc1p[(size_t)n * KSOI + kp] = __float2bfloat16(v);
        }
    } else if (bid < 2816) {
        int i = (bid - 2688) * 256 + tid;   // over 256*128
        int n = i >> 7, k = i & 127;
        Wc1hT[n * 128 + k] = __float2bfloat16(Wc1[(size_t)k * 256 + n]);
    } else {
        int i = (bid - 2816) * 256 + tid;   // over 256*32
        int n = i >> 5, k = i & 31;
        Wc1fT[n * 32 + k] = __float2bfloat16(Wc1[(size_t)(HO_DIM + NPAIR + k) * 256 + n]);
    }
}

// ---------------- K1: gram -> z partial (soi+first head) + MLP1 ----------------
// soi section: R7 verbatim. MLP1: K-chunk 128 (16 phases), A dbuf 2x8K @0/8K,
// B dbuf 2x64K @16K/80K. LDS 147456 total.
__global__ __launch_bounds__(512) void gram_z_mlp1(
    const float* __restrict__ x, const bf16* __restrict__ Wc1p,
    const bf16* __restrict__ Wc1fT, const bf16* __restrict__ W1T,
    const float* __restrict__ b1, float* __restrict__ z, bf16* __restrict__ h1) {
    constexpr int TI[10] = {0,0,0,0,1,1,1,2,2,3};
    constexpr int TJ[10] = {0,1,2,3,1,2,3,2,3,3};
    __shared__ __align__(16) char smraw[147456];
    bf16* Afirst = (bf16*)(smraw + 98304);

    const int tid = threadIdx.x;
    const int w = tid >> 6, l = tid & 63;
    const int lr = l & 15, lk = l >> 4;
    const int blk = blockIdx.x;
    const int batch0 = blk * 32 + w * 4;
    const int srow = tid >> 3, sks = tid & 7;        // soi 64-chunk staging
    const int colb = tid >> 4, ks16t = tid & 15;     // MLP1 128-chunk staging

    // ---- load x -> xa regs, first_order -> Afirst (R7 verbatim) ----
    bf16x8 xa[4][4];
#pragma unroll
    for (int bb = 0; bb < 4; ++bb) {
        float4 f[8];
#pragma unroll
        for (int ti = 0; ti < 4; ++ti) {
            const float* p = x + (size_t)(batch0 + bb) * 2048 + (ti * 16 + lr) * 32 + lk * 8;
            f[ti * 2]     = *(const float4*)p;
            f[ti * 2 + 1] = *(const float4*)(p + 4);
        }
        float fsum[8];
#pragma unroll
        for (int j = 0; j < 8; ++j) fsum[j] = 0.f;
#pragma unroll
        for (int ti = 0; ti < 4; ++ti) {
            float4 f0 = f[ti * 2];
            float4 f1 = f[ti * 2 + 1];
            bf16x8 t;
            t[0] = (__bf16)f0.x; t[1] = (__bf16)f0.y; t[2] = (__bf16)f0.z; t[3] = (__bf16)f0.w;
            t[4] = (__bf16)f1.x; t[5] = (__bf16)f1.y; t[6] = (__bf16)f1.z; t[7] = (__bf16)f1.w;
            xa[bb][ti] = t;
            fsum[0] += f0.x; fsum[1] += f0.y; fsum[2] += f0.z; fsum[3] += f0.w;
            fsum[4] += f1.x; fsum[5] += f1.y; fsum[6] += f1.z; fsum[7] += f1.w;
        }
#pragma unroll
        for (int m = 1; m < 16; m <<= 1)
#pragma unroll
            for (int j = 0; j < 8; ++j)
                fsum[j] += __shfl_xor(fsum[j], m, 64);
        if (lr == 0) {
            bf16x8 fv;
#pragma unroll
            for (int j = 0; j < 8; ++j) fv[j] = (__bf16)fsum[j];
            *(bf16x8*)(Afirst + (w * 4 + bb) * 32 + lk * 8) = fv;
        }
    }

    // ---- gram tile 0 -> A buf 0, stage B chunk 0 (R7 verbatim) ----
    const bf16* gBs[4];
#pragma unroll
    for (int s = 0; s < 4; ++s) {
        int col = s * 64 + srow;
        gBs[s] = Wc1p + (size_t)col * KSOI + ((sks ^ (col & 7)) * 8);
    }
    {
        f32x4 zero = {0.f, 0.f, 0.f, 0.f};
#pragma unroll
        for (int bb = 0; bb < 4; ++bb) {
            f32x4 g = __builtin_amdgcn_mfma_f32_16x16x32_bf16(xa[bb][0], xa[bb][0], zero, 0, 0, 0);
            int rowb = w * 4 + bb;
#pragma unroll
            for (int r = 0; r < 4; ++r) {
                int i = lk * 4 + r;
                int dw = i * 8 + (lr >> 1);
                *(bf16*)(smraw + rowb * 512 + soi_swz(dw, rowb) * 4 + (lr & 1) * 2) =
                    __float2bfloat16(g[r]);
            }
        }
        bf16* B0 = (bf16*)(smraw + 32768);
#pragma unroll
        for (int s = 0; s < 4; ++s)
            gload16(gBs[s], B0 + (s * 512 + tid) * 8);
    }
    __syncthreads();

    // ---- z accumulators: first_order mini-GEMM (K=32) (R7 verbatim) ----
    f32x4 acc[2][2];
    {
        bf16x8 af[2], bf_[2];
#pragma unroll
        for (int fm = 0; fm < 2; ++fm) {
            int row = fm * 16 + lr;
            af[fm] = *(const bf16x8*)(Afirst + row * 32 + lk * 8);
        }
#pragma unroll
        for (int fn = 0; fn < 2; ++fn) {
            int col = w * 32 + fn * 16 + lr;
            bf_[fn] = *(const bf16x8*)(Wc1fT + col * 32 + lk * 8);
        }
        f32x4 zero = {0.f, 0.f, 0.f, 0.f};
#pragma unroll
        for (int fm = 0; fm < 2; ++fm)
#pragma unroll
            for (int fn = 0; fn < 2; ++fn)
                acc[fm][fn] = __builtin_amdgcn_mfma_f32_16x16x32_bf16(af[fm], bf_[fn], zero, 0, 0, 0);
    }

    // ---- soi head GEMM: 10 tiles x 4 chunks of K=64 (R7 verbatim) ----
#pragma unroll
    for (int t = 0; t < 10; ++t) {
#pragma unroll
        for (int cc = 0; cc < 4; ++cc) {
            const int c = t * 4 + cc;
            char* at = smraw + ((t & 1) ? 16384 : 0);
            bf16* Bc = (bf16*)(smraw + 32768 + ((c & 1) ? 32768 : 0));
            bf16* Bn = (bf16*)(smraw + 32768 + ((c & 1) ? 0 : 32768));
            if (c < 39) {
#pragma unroll
                for (int s = 0; s < 4; ++s)
                    gload16(gBs[s] + (c + 1) * 64, Bn + (s * 512 + tid) * 8);
            }
            bf16x8 a[2][2], bfr[2][2];
#pragma unroll
            for (int kk2 = 0; kk2 < 2; ++kk2) {
                const int ks = cc * 2 + kk2;
#pragma unroll
                for (int fm = 0; fm < 2; ++fm) {
                    int row = fm * 16 + lr;
                    int i = ks * 2 + (lk >> 1);
                    int dw = i * 8 + (lk & 1) * 4;
                    a[fm][kk2] = *(const bf16x8*)(at + row * 512 + soi_swz(dw, row) * 4);
                }
#pragma unroll
                for (int fn = 0; fn < 2; ++fn) {
                    int bcol = w * 32 + fn * 16 + lr;
                    bfr[fn][kk2] = *(const bf16x8*)(Bc + bcol * 64 + (((kk2 * 4 + lk) ^ (bcol & 7)) * 8));
                }
            }
#pragma unroll
            for (int kk2 = 0; kk2 < 2; ++kk2)
#pragma unroll
                for (int fm = 0; fm < 2; ++fm)
#pragma unroll
                    for (int fn = 0; fn < 2; ++fn)
                        acc[fm][fn] = __builtin_amdgcn_mfma_f32_16x16x32_bf16(
                            a[fm][kk2], bfr[fn][kk2], acc[fm][fn], 0, 0, 0);
            if (cc == 3 && t < 9) {
                char* an = smraw + (((t + 1) & 1) ? 16384 : 0);
                f32x4 zero = {0.f, 0.f, 0.f, 0.f};
#pragma unroll
                for (int bb = 0; bb < 4; ++bb) {
                    f32x4 g = __builtin_amdgcn_mfma_f32_16x16x32_bf16(
                        xa[bb][TI[t + 1]], xa[bb][TJ[t + 1]], zero, 0, 0, 0);
                    int rowb = w * 4 + bb;
#pragma unroll
                    for (int r = 0; r < 4; ++r) {
                        int i = lk * 4 + r;
                        int dw = i * 8 + (lr >> 1);
                        *(bf16*)(an + rowb * 512 + soi_swz(dw, rowb) * 4 + (lr & 1) * 2) =
                            __float2bfloat16(g[r]);
                    }
                }
            }
            __syncthreads();
        }
    }

    // ---- store z partial (f32, row-major) ----
#pragma unroll
    for (int fm = 0; fm < 2; ++fm)
#pragma unroll
        for (int fn = 0; fn < 2; ++fn) {
            int col = w * 32 + fn * 16 + lr;
#pragma unroll
            for (int r = 0; r < 4; ++r) {
                int row = blk * 32 + fm * 16 + lk * 4 + r;
                z[(size_t)row * 256 + col] = acc[fm][fn][r];
            }
        }

    // ---------------- MLP1 phase: K-chunk 128, 16 phases ----------------
    bf16* MA0 = (bf16*)smraw;             // 8KB [32][128]
    bf16* MA1 = (bf16*)(smraw + 8192);
    bf16* MB0 = (bf16*)(smraw + 16384);   // 64KB [256 cols][128 k]
    bf16* MB1 = (bf16*)(smraw + 81920);   // 64KB
    const bf16* gW1b = W1T + (size_t)colb * 2048 + ((ks16t ^ (colb & 15)) * 8);
    const int ldst_off = colb * 128 + ks16t * 8;   // elems; byte = 16*tid (lane-linear)

    f32x4 acm[2][2];
#pragma unroll
    for (int fm = 0; fm < 2; ++fm)
#pragma unroll
        for (int fn = 0; fn < 2; ++fn)
            acm[fm][fn] = (f32x4){0.f, 0.f, 0.f, 0.f};

    // WRITEA2(pp): k-range [pp*128,(pp+1)*128) from xa into DST [32][128] swizzled
#define WRITEA2(pp, DST) { \
    const int lr0_ = ((pp) & 3) * 4; \
    int delta_ = lr - lr0_; \
    if (delta_ >= 0 && delta_ < 4) { \
        int slot_ = delta_ * 4 + lk; \
        _Pragma("unroll") \
        for (int bb_ = 0; bb_ < 4; ++bb_) { \
            int row_ = w * 4 + bb_; \
            *(bf16x8*)((DST) + row_ * 128 + ((slot_ ^ (row_ & 15)) * 8)) = xa[bb_][(pp) >> 2]; \
        } } }

    WRITEA2(0, MA0);
#pragma unroll
    for (int s = 0; s < 8; ++s)
        gload16(gW1b + (size_t)s * 32 * 2048, MB0 + s * 4096 + ldst_off);
    __syncthreads();

#pragma unroll
    for (int t = 0; t < 16; ++t) {
        bf16* Ac = (t & 1) ? MA1 : MA0;
        bf16* Bc = (t & 1) ? MB1 : MB0;
        bf16* An = (t & 1) ? MA0 : MA1;
        bf16* Bn = (t & 1) ? MB0 : MB1;
        if (t < 15) {
#pragma unroll
            for (int s = 0; s < 8; ++s)
                gload16(gW1b + (size_t)s * 32 * 2048 + (t + 1) * 128, Bn + s * 4096 + ldst_off);
        }
#pragma unroll
        for (int kk = 0; kk < 4; ++kk) {
            const int q = kk * 4 + lk;
            const int so = (q ^ lr) * 8;    // row&15 == lr and col&15 == lr
            bf16x8 a0 = *(const bf16x8*)(Ac + lr * 128 + so);
            bf16x8 a1 = *(const bf16x8*)(Ac + (16 + lr) * 128 + so);
            bf16x8 b0 = *(const bf16x8*)(Bc + (w * 32 + lr) * 128 + so);
            bf16x8 b1 = *(const bf16x8*)(Bc + (w * 32 + 16 + lr) * 128 + so);
            acm[0][0] = __builtin_amdgcn_mfma_f32_16x16x32_bf16(a0, b0, acm[0][0], 0, 0, 0);
            acm[0][1] = __builtin_amdgcn_mfma_f32_16x16x32_bf16(a0, b1, acm[0][1], 0, 0, 0);
            acm[1][0] = __builtin_amdgcn_mfma_f32_16x16x32_bf16(a1, b0, acm[1][0], 0, 0, 0);
            acm[1][1] = __builtin_amdgcn_mfma_f32_16x16x32_bf16(a1, b1, acm[1][1], 0, 0, 0);
        }
        if (t < 15) WRITEA2(t + 1, An);
        __syncthreads();
    }
#undef WRITEA2

#pragma unroll
    for (int fm = 0; fm < 2; ++fm) {
#pragma unroll
        for (int fn = 0; fn < 2; ++fn) {
            int col = w * 32 + fn * 16 + lr;
            float bv = b1[col];
#pragma unroll
            for (int r = 0; r < 4; ++r) {
                float v = selu_f(acm[fm][fn][r] + bv);
                int row = blk * 32 + fm * 16 + lk * 4 + r;
                h1[(size_t)row * 256 + col] = __float2bfloat16(v);
            }
        }
    }
}

// ---------------- K2: MLP2 + MLP3 + head-hoi + relu*Wc2 -> out (R7 verbatim) ----------------
__global__ __launch_bounds__(512) void mlp23_head(
    const bf16* __restrict__ h1, const bf16* __restrict__ W2T, const float* __restrict__ b2,
    const bf16* __restrict__ W3Tsw, const float* __restrict__ b3,
    const bf16* __restrict__ Wc1hT, const float* __restrict__ z,
    const float* __restrict__ bc1, const float* __restrict__ Wc2,
    const float* __restrict__ bc2, float* __restrict__ Out) {
    __shared__ __align__(16) char smraw[147456];
    __shared__ float red[4][64];
    bf16* Abuf0 = (bf16*)smraw;
    bf16* Abuf1 = (bf16*)(smraw + 8192);
    bf16* Bbuf0 = (bf16*)(smraw + 16384);
    bf16* Bbuf1 = (bf16*)(smraw + 49152);
    bf16* w3l   = (bf16*)(smraw + 81920);
    bf16* h2sw  = (bf16*)smraw;
    bf16* hoisw = (bf16*)(smraw + 49152);

    const int tid = threadIdx.x;
    const int w = tid >> 6, l = tid & 63;
    const int lr = l & 15, lk = l >> 4;
    const int wm = w >> 2, wn = w & 3;
    const int rowblk = blockIdx.x * 64;
    const int srow = tid >> 3, sks = tid & 7;

#pragma unroll
    for (int s = 0; s < 8; ++s)
        gload16(W3Tsw + (size_t)(s * 512 + tid) * 8, w3l + (s * 512 + tid) * 8);

    const bf16* gA = h1 + (size_t)(rowblk + srow) * 256 + ((sks ^ (srow & 7)) * 8);
    const bf16* gBs[4];
#pragma unroll
    for (int s = 0; s < 4; ++s) {
        int col = s * 64 + srow;
        gBs[s] = W2T + (size_t)col * 256 + ((sks ^ (col & 7)) * 8);
    }
    int aoff[2][2], boff[4][2];
#pragma unroll
    for (int fm = 0; fm < 2; ++fm) {
        int arow = wm * 32 + fm * 16 + lr;
#pragma unroll
        for (int kk = 0; kk < 2; ++kk)
            aoff[fm][kk] = arow * 64 + (((kk * 4 + lk) ^ (arow & 7)) * 8);
    }
#pragma unroll
    for (int fn = 0; fn < 4; ++fn) {
        int bcol = wn * 64 + fn * 16 + lr;
#pragma unroll
        for (int kk = 0; kk < 2; ++kk)
            boff[fn][kk] = bcol * 64 + (((kk * 4 + lk) ^ (bcol & 7)) * 8);
    }

    f32x4 acc[2][4];
#pragma unroll
    for (int fm = 0; fm < 2; ++fm)
#pragma unroll
        for (int fn = 0; fn < 4; ++fn)
            acc[fm][fn] = (f32x4){0.f, 0.f, 0.f, 0.f};

    gload16(gA, Abuf0 + tid * 8);
#pragma unroll
    for (int s = 0; s < 4; ++s)
        gload16(gBs[s], Bbuf0 + (s * 512 + tid) * 8);
    __syncthreads();

#pragma unroll
    for (int t = 0; t < 4; ++t) {
        bf16* Ac = (t & 1) ? Abuf1 : Abuf0;
        bf16* Bc = (t & 1) ? Bbuf1 : Bbuf0;
        bf16* An = (t & 1) ? Abuf0 : Abuf1;
        bf16* Bn = (t & 1) ? Bbuf0 : Bbuf1;
        if (t < 3) {
            gload16(gA + (size_t)(t + 1) * 64, An + tid * 8);
#pragma unroll
            for (int s = 0; s < 4; ++s)
                gload16(gBs[s] + (size_t)(t + 1) * 64, Bn + (s * 512 + tid) * 8);
        }
        bf16x8 a[2][2], bfr[4][2];
#pragma unroll
        for (int fm = 0; fm < 2; ++fm)
#pragma unroll
            for (int kk = 0; kk < 2; ++kk)
                a[fm][kk] = *(const bf16x8*)(Ac + aoff[fm][kk]);
#pragma unroll
        for (int fn = 0; fn < 4; ++fn)
#pragma unroll
            for (int kk = 0; kk < 2; ++kk)
                bfr[fn][kk] = *(const bf16x8*)(Bc + boff[fn][kk]);
#pragma unroll
        for (int kk = 0; kk < 2; ++kk)
#pragma unroll
            for (int fm = 0; fm < 2; ++fm)
#pragma unroll
                for (int fn = 0; fn < 4; ++fn)
                    acc[fm][fn] = __builtin_amdgcn_mfma_f32_16x16x32_bf16(
                        a[fm][kk], bfr[fn][kk], acc[fm][fn], 0, 0, 0);
        __syncthreads();
    }

    // h2 (selu) -> LDS swizzled [64][256]
#pragma unroll
    for (int fm = 0; fm < 2; ++fm) {
#pragma unroll
        for (int fn = 0; fn < 4; ++fn) {
            int col = wn * 64 + fn * 16 + lr;
            float bv = b2[col];
#pragma unroll
            for (int r = 0; r < 4; ++r) {
                float v = selu_f(acc[fm][fn][r] + bv);
                int row = wm * 32 + fm * 16 + lk * 4 + r;
                h2sw[row * 256 + (((col >> 3) ^ (row & 7)) * 8) + (col & 7)] = __float2bfloat16(v);
            }
        }
    }
    __syncthreads();

    // MLP3: hoi = h2 @ W3 + b3 -> hoisw [64][128] swizzled
    f32x4 acc2[2][2];
#pragma unroll
    for (int fm = 0; fm < 2; ++fm)
#pragma unroll
        for (int fn = 0; fn < 2; ++fn)
            acc2[fm][fn] = (f32x4){0.f, 0.f, 0.f, 0.f};
#pragma unroll
    for (int ks = 0; ks < 8; ++ks) {
        bf16x8 a2[2], b2f[2];
#pragma unroll
        for (int fm = 0; fm < 2; ++fm) {
            int arow = wm * 32 + fm * 16 + lr;
            a2[fm] = *(const bf16x8*)(h2sw + arow * 256 + (((ks * 4 + lk) ^ (arow & 7)) * 8));
        }
#pragma unroll
        for (int fn = 0; fn < 2; ++fn) {
            int ncol = wn * 32 + fn * 16 + lr;
            b2f[fn] = *(const bf16x8*)(w3l + ncol * 256 + (((ks * 4 + lk) ^ (ncol & 7)) * 8));
        }
#pragma unroll
        for (int fm = 0; fm < 2; ++fm)
#pragma unroll
            for (int fn = 0; fn < 2; ++fn)
                acc2[fm][fn] = __builtin_amdgcn_mfma_f32_16x16x32_bf16(
                    a2[fm], b2f[fn], acc2[fm][fn], 0, 0, 0);
    }
#pragma unroll
    for (int fm = 0; fm < 2; ++fm) {
#pragma unroll
        for (int fn = 0; fn < 2; ++fn) {
            int col = wn * 32 + fn * 16 + lr;
            float bv = b3[col];
#pragma unroll
            for (int r = 0; r < 4; ++r) {
                float v = acc2[fm][fn][r] + bv;
                int row = wm * 32 + fm * 16 + lk * 4 + r;
                hoisw[row * 128 + (((col >> 3) ^ (row & 7)) * 8) + (col & 7)] = __float2bfloat16(v);
            }
        }
    }
    __syncthreads();

    // head-hoi: acc_h = z + hoi @ Wc1hT (K=128)
    f32x4 acch[2][4];
#pragma unroll
    for (int fm = 0; fm < 2; ++fm)
#pragma unroll
        for (int fn = 0; fn < 4; ++fn) {
            int col = wn * 64 + fn * 16 + lr;
#pragma unroll
            for (int r = 0; r < 4; ++r) {
                int row = rowblk + wm * 32 + fm * 16 + lk * 4 + r;
                acch[fm][fn][r] = z[(size_t)row * 256 + col];
            }
        }
#pragma unroll
    for (int ks = 0; ks < 4; ++ks) {
        bf16x8 a3[2], b3f[4];
#pragma unroll
        for (int fm = 0; fm < 2; ++fm) {
            int arow = wm * 32 + fm * 16 + lr;
            a3[fm] = *(const bf16x8*)(hoisw + arow * 128 + (((ks * 4 + lk) ^ (arow & 7)) * 8));
        }
#pragma unroll
        for (int fn = 0; fn < 4; ++fn) {
            int col = wn * 64 + fn * 16 + lr;
            b3f[fn] = *(const bf16x8*)(Wc1hT + col * 128 + ks * 32 + lk * 8);
        }
#pragma unroll
        for (int fm = 0; fm < 2; ++fm)
#pragma unroll
            for (int fn = 0; fn < 4; ++fn)
                acch[fm][fn] = __builtin_amdgcn_mfma_f32_16x16x32_bf16(
                    a3[fm], b3f[fn], acch[fm][fn], 0, 0, 0);
    }

    // relu + dot Wc2 + reduce -> out
    float part[2][4];
#pragma unroll
    for (int fm = 0; fm < 2; ++fm)
#pragma unroll
        for (int r = 0; r < 4; ++r) part[fm][r] = 0.f;
#pragma unroll
    for (int fm = 0; fm < 2; ++fm) {
#pragma unroll
        for (int fn = 0; fn < 4; ++fn) {
            int col = wn * 64 + fn * 16 + lr;
            float bv = bc1[col];
            float wv = Wc2[col];
#pragma unroll
            for (int r = 0; r < 4; ++r) {
                float v = fmaxf(acch[fm][fn][r] + bv, 0.f);
                part[fm][r] += v * wv;
            }
        }
    }
#pragma unroll
    for (int fm = 0; fm < 2; ++fm)
#pragma unroll
        for (int r = 0; r < 4; ++r)
#pragma unroll
            for (int m = 1; m < 16; m <<= 1)
                part[fm][r] += __shfl_xor(part[fm][r], m, 64);
    if (lr == 0) {
#pragma unroll
        for (int fm = 0; fm < 2; ++fm)
#pragma unroll
            for (int r = 0; r < 4; ++r)
                red[wn][wm * 32 + fm * 16 + lk * 4 + r] = part[fm][r];
    }
    __syncthreads();
    if (tid < 64)
        Out[rowblk + tid] = red[0][tid] + red[1][tid] + red[2][tid] + red[3][tid] + bc2[0];
}

extern "C" void kernel_launch(void* const* d_in, const int* in_sizes, int n_in,
                              void* d_out, int out_size, void* d_ws, size_t ws_size,
                              hipStream_t stream) {
    const float* x   = (const float*)d_in[0];
    const float* W1  = (const float*)d_in[1];
    const float* b1  = (const float*)d_in[2];
    const float* W2  = (const float*)d_in[3];
    const float* b2  = (const float*)d_in[4];
    const float* W3  = (const float*)d_in[5];
    const float* b3  = (const float*)d_in[6];
    const float* Wc1 = (const float*)d_in[7];
    const float* bc1 = (const float*)d_in[8];
    const float* Wc2 = (const float*)d_in[9];
    const float* bc2 = (const float*)d_in[10];
    float* out = (float*)d_out;

    char* ws = (char*)d_ws;
    bf16* W1T   = (bf16*)ws; ws += (size_t)256 * 2048 * 2;
    bf16* W2T   = (bf16*)ws; ws += (size_t)256 * 256 * 2;
    bf16* W3Tsw = (bf16*)ws; ws += (size_t)128 * 256 * 2;
    bf16* Wc1p  = (bf16*)ws; ws += (size_t)256 * KSOI * 2;
    bf16* Wc1hT = (bf16*)ws; ws += (size_t)256 * 128 * 2;
    bf16* Wc1fT = (bf16*)ws; ws += (size_t)256 * 32 * 2;
    bf16* h1    = (bf16*)ws; ws += (size_t)BATCH * H_DIM * 2;
    float* z    = (float*)ws; ws += (size_t)BATCH * 256 * 4;

    prep<<<2848, 256, 0, stream>>>(W1, W2, W3, Wc1, W1T, W2T, W3Tsw, Wc1p, Wc1hT, Wc1fT);
    gram_z_mlp1<<<512, 512, 0, stream>>>(x, Wc1p, Wc1fT, W1T, b1, z, h1);
    mlp23_head<<<256, 512, 0, stream>>>(h1, W2T, b2, W3Tsw, b3, Wc1hT, z, bc1, Wc2, bc2, out);
}